// Round 1
// baseline (1500.645 us; speedup 1.0000x reference)
//
#include <hip/hip_runtime.h>
#include <hip/hip_bf16.h>

#define NB 32
#define CH 64
#define TF 300
#define VJ 25
#define NSUB 3
#define ICB 16
#define KW 9
#define EPSB 1e-5f

#define TVsz (TF*VJ)          // 7500
#define CTVsz (CH*TF*VJ)      // 480000
#define TOTAL (NB*CTVsz)      // 15360000
#define PCCOUNT (NB*TF*VJ)    // 240000 elements per channel for BN

#define TCHUNK 10
#define TCLEN 30

// ---------------- Wt transpose: [o][c][k] -> [k][c][o] ----------------
__global__ void k_wtT(const float* __restrict__ Wt, float* __restrict__ wtT) {
    int e = blockIdx.x * 256 + threadIdx.x;
    if (e >= CH*CH*KW) return;
    int o = e / (CH*KW);
    int c = (e / KW) % CH;
    int k = e % KW;
    wtT[(k*CH + c)*CH + o] = Wt[e];
}

// ---------------- attention Gram partial: M[u,w] += sum_{o,t} a[o,t,u]*b[o,t,w] ----
__global__ __launch_bounds__(256) void k_attn_partial(
    const float* __restrict__ x, const float* __restrict__ Wa, const float* __restrict__ ba,
    const float* __restrict__ Wb, const float* __restrict__ bb, float* __restrict__ Mbuf)
{
    __shared__ __align__(16) float xs[CH*VJ];     // [c*25+v]
    __shared__ __align__(16) float Wab[32*CH];    // rows 0..15 = Wa_i, 16..31 = Wb_i
    __shared__ __align__(16) float ab[32*VJ];     // [r*25+v], r<16 a, r>=16 b

    int b = blockIdx.x;
    int i   = b / (NB*TCHUNK);
    int rem = b % (NB*TCHUNK);
    int n   = rem / TCHUNK;
    int tc  = rem % TCHUNK;
    int tid = threadIdx.x;

    for (int e = tid; e < 32*CH; e += 256) {
        int r = e >> 6, c = e & 63;
        Wab[e] = (r < 16) ? Wa[(i*ICB + r)*CH + c] : Wb[(i*ICB + (r-16))*CH + c];
    }

    int v = tid % 25, g = tid / 25;
    bool act = (tid < 200);
    int r0 = g * 4;
    float bias[4];
    if (act) {
        #pragma unroll
        for (int rr = 0; rr < 4; ++rr) {
            int r = r0 + rr;
            bias[rr] = (r < 16) ? ba[i*ICB + r] : bb[i*ICB + (r-16)];
        }
    }

    float Mloc[3] = {0.f, 0.f, 0.f};
    const float* xg = x + (long)n * CTVsz;

    for (int t = tc*TCLEN; t < tc*TCLEN + TCLEN; ++t) {
        __syncthreads();
        for (int e = tid; e < CH*VJ; e += 256) {
            int c = e / 25, vv = e % 25;
            xs[e] = xg[c*TVsz + t*VJ + vv];
        }
        __syncthreads();
        if (act) {
            float a0=0.f, a1=0.f, a2=0.f, a3=0.f;
            #pragma unroll
            for (int c = 0; c < CH; c += 4) {
                float x0 = xs[(c+0)*VJ + v];
                float x1 = xs[(c+1)*VJ + v];
                float x2 = xs[(c+2)*VJ + v];
                float x3 = xs[(c+3)*VJ + v];
                float4 w0 = *(const float4*)&Wab[(r0+0)*CH + c];
                float4 w1 = *(const float4*)&Wab[(r0+1)*CH + c];
                float4 w2 = *(const float4*)&Wab[(r0+2)*CH + c];
                float4 w3 = *(const float4*)&Wab[(r0+3)*CH + c];
                a0 += w0.x*x0 + w0.y*x1 + w0.z*x2 + w0.w*x3;
                a1 += w1.x*x0 + w1.y*x1 + w1.z*x2 + w1.w*x3;
                a2 += w2.x*x0 + w2.y*x1 + w2.z*x2 + w2.w*x3;
                a3 += w3.x*x0 + w3.y*x1 + w3.z*x2 + w3.w*x3;
            }
            ab[(r0+0)*VJ + v] = a0 + bias[0];
            ab[(r0+1)*VJ + v] = a1 + bias[1];
            ab[(r0+2)*VJ + v] = a2 + bias[2];
            ab[(r0+3)*VJ + v] = a3 + bias[3];
        }
        __syncthreads();
        int p = 0;
        for (int e = tid; e < 625; e += 256, ++p) {
            int u = e / 25, w = e % 25;
            float s = 0.f;
            #pragma unroll
            for (int o = 0; o < 16; ++o)
                s += ab[o*VJ + u] * ab[(16+o)*VJ + w];
            Mloc[p] += s;
        }
    }
    int p = 0;
    for (int e = tid; e < 625; e += 256, ++p)
        atomicAdd(&Mbuf[(i*NB + n)*625 + e], Mloc[p]);
}

// ---------------- column softmax (axis=-2) * scale, then += A+PA, in place ----
__global__ void k_softmax(const float* __restrict__ A, const float* __restrict__ PA,
                          float* __restrict__ Mbuf) {
    int b = blockIdx.x;          // = i*NB + n
    int i = b / NB;
    int w = threadIdx.x;
    if (w >= 25) return;
    float* M = Mbuf + b*625;
    const float scale = 1.0f / (float)(ICB * TF);
    float col[25];
    float mx = -1e30f;
    #pragma unroll
    for (int u = 0; u < 25; ++u) { col[u] = M[u*25 + w] * scale; mx = fmaxf(mx, col[u]); }
    float s = 0.f;
    #pragma unroll
    for (int u = 0; u < 25; ++u) { col[u] = __expf(col[u] - mx); s += col[u]; }
    float inv = 1.0f / s;
    #pragma unroll
    for (int u = 0; u < 25; ++u)
        M[u*25 + w] = col[u]*inv + A[i*625 + u*25 + w] + PA[i*625 + u*25 + w];
}

// ---------------- y = sum_i Wd_i @ (x @ attn_i) + sum_i bd_i ----------------
__global__ __launch_bounds__(256) void k_y(
    const float* __restrict__ x, const float* __restrict__ attn,
    const float* __restrict__ Wd, const float* __restrict__ bd,
    float* __restrict__ ybuf)
{
    __shared__ __align__(16) float xs[CH*4*28];   // [(c*4+tq)*28 + u]
    __shared__ __align__(16) float zs[CH*100];    // [c*100 + tq*25+v]
    __shared__ __align__(16) float wdT[CH*CH];    // [c*64+o]
    __shared__ __align__(16) float atT[25*28];    // [v*28+u]

    int b = blockIdx.x;
    int n = b / 75, tt = b % 75;
    int t0 = tt * 4;
    int tid = threadIdx.x;
    int ty = tid >> 4, tx = tid & 15;
    int o0 = ty * 4;

    const float* xg = x + (long)n*CTVsz + t0*VJ;
    for (int e = tid; e < CH*100; e += 256) {
        int c = e / 100, tv = e % 100;
        int tq = tv / 25, u = tv % 25;
        xs[(c*4 + tq)*28 + u] = xg[c*TVsz + tv];
    }

    float acc[4][7];
    #pragma unroll
    for (int rr = 0; rr < 4; ++rr)
        #pragma unroll
        for (int j = 0; j < 7; ++j) acc[rr][j] = 0.f;

    for (int i = 0; i < NSUB; ++i) {
        __syncthreads();
        for (int e = tid; e < CH*CH; e += 256) {
            int c = e >> 6, o = e & 63;
            wdT[e] = Wd[i*CH*CH + o*CH + c];
        }
        for (int e = tid; e < 625; e += 256) {
            int vv = e / 25, u = e % 25;
            atT[vv*28 + u] = attn[(i*NB + n)*625 + u*25 + vv];
        }
        __syncthreads();
        // z phase: z[c][tq][v] = sum_u x[c][tq][u] * attn[u][v]
        for (int e = tid; e < CH*VJ; e += 256) {
            int c = e / 25, vv = e % 25;
            const float* xc = &xs[c*4*28];
            const float* at = &atT[vv*28];
            float z0=0.f, z1=0.f, z2=0.f, z3=0.f;
            #pragma unroll
            for (int u = 0; u < 24; u += 4) {
                float4 a4 = *(const float4*)&at[u];
                float4 p0 = *(const float4*)&xc[0*28 + u];
                float4 p1 = *(const float4*)&xc[1*28 + u];
                float4 p2 = *(const float4*)&xc[2*28 + u];
                float4 p3 = *(const float4*)&xc[3*28 + u];
                z0 += a4.x*p0.x + a4.y*p0.y + a4.z*p0.z + a4.w*p0.w;
                z1 += a4.x*p1.x + a4.y*p1.y + a4.z*p1.z + a4.w*p1.w;
                z2 += a4.x*p2.x + a4.y*p2.y + a4.z*p2.z + a4.w*p2.w;
                z3 += a4.x*p3.x + a4.y*p3.y + a4.z*p3.z + a4.w*p3.w;
            }
            float a24 = at[24];
            z0 += a24*xc[0*28+24]; z1 += a24*xc[1*28+24];
            z2 += a24*xc[2*28+24]; z3 += a24*xc[3*28+24];
            zs[c*100 + 0*25 + vv] = z0;
            zs[c*100 + 1*25 + vv] = z1;
            zs[c*100 + 2*25 + vv] = z2;
            zs[c*100 + 3*25 + vv] = z3;
        }
        __syncthreads();
        // Wd phase: acc[o][tv] += sum_c wdT[c][o] * zs[c][tv]
        for (int c = 0; c < CH; ++c) {
            float4 w4 = *(const float4*)&wdT[c*CH + o0];
            #pragma unroll
            for (int j = 0; j < 7; ++j) {
                int tv = tx + 16*j;
                if (tv < 100) {
                    float zv = zs[c*100 + tv];
                    acc[0][j] += w4.x*zv;
                    acc[1][j] += w4.y*zv;
                    acc[2][j] += w4.z*zv;
                    acc[3][j] += w4.w*zv;
                }
            }
        }
    }

    float bds[4];
    #pragma unroll
    for (int rr = 0; rr < 4; ++rr)
        bds[rr] = bd[o0+rr] + bd[CH + o0+rr] + bd[2*CH + o0+rr];

    float* yg = ybuf + (long)n*CTVsz + t0*VJ;
    #pragma unroll
    for (int rr = 0; rr < 4; ++rr)
        #pragma unroll
        for (int j = 0; j < 7; ++j) {
            int tv = tx + 16*j;
            if (tv < 100) yg[(o0+rr)*TVsz + tv] = acc[rr][j] + bds[rr];
        }
}

// ---------------- per-channel sum / sumsq reduction ----------------
__global__ __launch_bounds__(256) void k_bnstats(const float* __restrict__ src,
                                                 float* __restrict__ s1, float* __restrict__ s2) {
    int nc = blockIdx.x;
    int c = nc & 63;
    const float* p = src + (long)nc * TVsz;
    float s = 0.f, q = 0.f;
    for (int e = threadIdx.x; e < TVsz; e += 256) {
        float v = p[e];
        s += v; q += v*v;
    }
    #pragma unroll
    for (int off = 32; off; off >>= 1) {
        s += __shfl_down(s, off, 64);
        q += __shfl_down(q, off, 64);
    }
    __shared__ float rs[4], rq[4];
    int wid = threadIdx.x >> 6, lane = threadIdx.x & 63;
    if (lane == 0) { rs[wid] = s; rq[wid] = q; }
    __syncthreads();
    if (threadIdx.x == 0) {
        atomicAdd(s1 + c, rs[0]+rs[1]+rs[2]+rs[3]);
        atomicAdd(s2 + c, rq[0]+rq[1]+rq[2]+rq[3]);
    }
}

// ---------------- y = relu(bn1(y) + x), in place ----------------
__global__ void k_bn1(const float* __restrict__ x, const float* __restrict__ g1, const float* __restrict__ b1,
                      const float* __restrict__ s1, const float* __restrict__ s2,
                      float* __restrict__ ybuf) {
    const float invN = 1.0f / (float)PCCOUNT;
    int stride = gridDim.x * blockDim.x;
    for (int idx = blockIdx.x*blockDim.x + threadIdx.x; idx < TOTAL; idx += stride) {
        int c = (idx / TVsz) & 63;
        float m  = s1[c] * invN;
        float vr = s2[c] * invN - m*m;
        float val = (ybuf[idx] - m) * rsqrtf(vr + EPSB) * g1[c] + b1[c] + x[idx];
        ybuf[idx] = fmaxf(val, 0.f);
    }
}

// ---------------- temporal conv (9,1), pad 4, + bt ----------------
__global__ __launch_bounds__(256) void k_tconv(
    const float* __restrict__ y2, const float* __restrict__ wtT, const float* __restrict__ bt,
    float* __restrict__ yc)
{
    __shared__ __align__(16) float ys[CH*300];   // [c*300 + tl*25+v], tl=0..11
    int b = blockIdx.x;
    int n = b / 75, tt = b % 75;
    int t0 = tt * 4;
    int tid = threadIdx.x;

    const float* yg = y2 + (long)n * CTVsz;
    for (int e = tid; e < CH*300; e += 256) {
        int c = e / 300, q = e % 300;
        int tg = t0 - 4 + q/25;
        int v = q % 25;
        ys[e] = (tg >= 0 && tg < TF) ? yg[c*TVsz + tg*VJ + v] : 0.f;
    }
    __syncthreads();

    int ty = tid >> 4, tx = tid & 15;
    int o0 = ty * 4;
    float acc[4][7];
    #pragma unroll
    for (int rr = 0; rr < 4; ++rr)
        #pragma unroll
        for (int j = 0; j < 7; ++j) acc[rr][j] = 0.f;

    for (int k = 0; k < KW; ++k) {
        const float* wk = wtT + k*CH*CH;
        for (int c = 0; c < CH; ++c) {
            float4 w4 = *(const float4*)&wk[c*CH + o0];
            #pragma unroll
            for (int j = 0; j < 7; ++j) {
                int tv = tx + 16*j;
                if (tv < 100) {
                    float yv = ys[c*300 + tv + 25*k];
                    acc[0][j] += w4.x*yv;
                    acc[1][j] += w4.y*yv;
                    acc[2][j] += w4.z*yv;
                    acc[3][j] += w4.w*yv;
                }
            }
        }
    }

    float* og = yc + (long)n*CTVsz + t0*VJ;
    #pragma unroll
    for (int rr = 0; rr < 4; ++rr) {
        float bo = bt[o0 + rr];
        #pragma unroll
        for (int j = 0; j < 7; ++j) {
            int tv = tx + 16*j;
            if (tv < 100) og[(o0+rr)*TVsz + tv] = acc[rr][j] + bo;
        }
    }
}

// ---------------- out = relu(bn2(yc) + x), f32 ----------------
__global__ void k_out(const float* __restrict__ x, const float* __restrict__ g2, const float* __restrict__ b2,
                      const float* __restrict__ s1, const float* __restrict__ s2,
                      const float* __restrict__ yc, float* __restrict__ out) {
    const float invN = 1.0f / (float)PCCOUNT;
    int stride = gridDim.x * blockDim.x;
    for (int idx = blockIdx.x*blockDim.x + threadIdx.x; idx < TOTAL; idx += stride) {
        int c = (idx / TVsz) & 63;
        float m  = s1[c] * invN;
        float vr = s2[c] * invN - m*m;
        float val = (yc[idx] - m) * rsqrtf(vr + EPSB) * g2[c] + b2[c] + x[idx];
        out[idx] = fmaxf(val, 0.f);
    }
}

extern "C" void kernel_launch(void* const* d_in, const int* in_sizes, int n_in,
                              void* d_out, int out_size, void* d_ws, size_t ws_size,
                              hipStream_t stream) {
    const float* x  = (const float*)d_in[0];
    const float* A  = (const float*)d_in[1];
    const float* PA = (const float*)d_in[2];
    const float* Wa = (const float*)d_in[3];
    const float* ba = (const float*)d_in[4];
    const float* Wb = (const float*)d_in[5];
    const float* bb = (const float*)d_in[6];
    const float* Wd = (const float*)d_in[7];
    const float* bd = (const float*)d_in[8];
    const float* g1 = (const float*)d_in[9];
    const float* b1 = (const float*)d_in[10];
    const float* Wt = (const float*)d_in[11];
    const float* bt = (const float*)d_in[12];
    const float* g2 = (const float*)d_in[13];
    const float* b2 = (const float*)d_in[14];

    float* ws    = (float*)d_ws;
    float* Mbuf  = ws;                       // NSUB*NB*625 = 60000
    float* stats = ws + 60000;               // 256 (s1,s2 for bn1; s1,s2 for bn2)
    float* ybuf  = ws + 60256;               // 15360000
    float* ycbuf = ybuf + TOTAL;             // 15360000
    float* wtT   = ycbuf + TOTAL;            // 36864

    hipMemsetAsync(Mbuf, 0, (60000 + 256)*sizeof(float), stream);
    k_wtT<<<(CH*CH*KW + 255)/256, 256, 0, stream>>>(Wt, wtT);
    k_attn_partial<<<NSUB*NB*TCHUNK, 256, 0, stream>>>(x, Wa, ba, Wb, bb, Mbuf);
    k_softmax<<<NSUB*NB, 32, 0, stream>>>(A, PA, Mbuf);
    k_y<<<NB*75, 256, 0, stream>>>(x, Mbuf, Wd, bd, ybuf);
    k_bnstats<<<NB*CH, 256, 0, stream>>>(ybuf, stats, stats + 64);
    k_bn1<<<2048, 256, 0, stream>>>(x, g1, b1, stats, stats + 64, ybuf);
    k_tconv<<<NB*75, 256, 0, stream>>>(ybuf, wtT, bt, ycbuf);
    k_bnstats<<<NB*CH, 256, 0, stream>>>(ycbuf, stats + 128, stats + 192);
    k_out<<<2048, 256, 0, stream>>>(x, g2, b2, stats + 128, stats + 192, ycbuf, (float*)d_out);
}

// Round 2
// 611.914 us; speedup vs baseline: 2.4524x; 2.4524x over previous
//
#include <hip/hip_runtime.h>
#include <hip/hip_bf16.h>

#define NB 32
#define CH 64
#define TF 300
#define VJ 25
#define NSUB 3
#define ICB 16
#define KW 9
#define EPSB 1e-5f

#define TVsz (TF*VJ)          // 7500
#define CTVsz (CH*TF*VJ)      // 480000
#define TOTAL (NB*CTVsz)      // 15360000
#define PCCOUNT (NB*TF*VJ)    // 240000

#define TCHUNK 10
#define TCLEN 30

typedef __attribute__((ext_vector_type(8))) short s16x8;
typedef __attribute__((ext_vector_type(4))) float f32x4;

__device__ __forceinline__ unsigned short f2bf(float v) {
    __hip_bfloat16 h = __float2bfloat16(v);
    return *(unsigned short*)&h;
}
__device__ __forceinline__ float bf2f(unsigned int u) {
    return __uint_as_float(u << 16);
}

// ---------------- Wt repack: [o][c][k] f32 -> [k][o][c] bf16 ----------------
__global__ void k_wtT(const float* __restrict__ Wt, unsigned short* __restrict__ awT) {
    int e = blockIdx.x * 256 + threadIdx.x;
    if (e >= CH*CH*KW) return;
    int o = e / (CH*KW);
    int c = (e / KW) % CH;
    int k = e % KW;
    awT[(k*CH + o)*CH + c] = f2bf(Wt[e]);
}

// ---------------- attention Gram partial ----------------
__global__ __launch_bounds__(256) void k_attn_partial(
    const float* __restrict__ x, const float* __restrict__ Wa, const float* __restrict__ ba,
    const float* __restrict__ Wb, const float* __restrict__ bb, float* __restrict__ Mbuf)
{
    __shared__ __align__(16) float xs[CH*VJ];
    __shared__ __align__(16) float Wab[32*CH];
    __shared__ __align__(16) float ab[32*VJ];

    int b = blockIdx.x;
    int i   = b / (NB*TCHUNK);
    int rem = b % (NB*TCHUNK);
    int n   = rem / TCHUNK;
    int tc  = rem % TCHUNK;
    int tid = threadIdx.x;

    for (int e = tid; e < 32*CH; e += 256) {
        int r = e >> 6, c = e & 63;
        Wab[e] = (r < 16) ? Wa[(i*ICB + r)*CH + c] : Wb[(i*ICB + (r-16))*CH + c];
    }

    int v = tid % 25, g = tid / 25;
    bool act = (tid < 200);
    int r0 = g * 4;
    float bias[4];
    if (act) {
        #pragma unroll
        for (int rr = 0; rr < 4; ++rr) {
            int r = r0 + rr;
            bias[rr] = (r < 16) ? ba[i*ICB + r] : bb[i*ICB + (r-16)];
        }
    }

    float Mloc[3] = {0.f, 0.f, 0.f};
    const float* xg = x + (long)n * CTVsz;

    for (int t = tc*TCLEN; t < tc*TCLEN + TCLEN; ++t) {
        __syncthreads();
        for (int e = tid; e < CH*VJ; e += 256) {
            int c = e / 25, vv = e % 25;
            xs[e] = xg[c*TVsz + t*VJ + vv];
        }
        __syncthreads();
        if (act) {
            float a0=0.f, a1=0.f, a2=0.f, a3=0.f;
            #pragma unroll
            for (int c = 0; c < CH; c += 4) {
                float x0 = xs[(c+0)*VJ + v];
                float x1 = xs[(c+1)*VJ + v];
                float x2 = xs[(c+2)*VJ + v];
                float x3 = xs[(c+3)*VJ + v];
                float4 w0 = *(const float4*)&Wab[(r0+0)*CH + c];
                float4 w1 = *(const float4*)&Wab[(r0+1)*CH + c];
                float4 w2 = *(const float4*)&Wab[(r0+2)*CH + c];
                float4 w3 = *(const float4*)&Wab[(r0+3)*CH + c];
                a0 += w0.x*x0 + w0.y*x1 + w0.z*x2 + w0.w*x3;
                a1 += w1.x*x0 + w1.y*x1 + w1.z*x2 + w1.w*x3;
                a2 += w2.x*x0 + w2.y*x1 + w2.z*x2 + w2.w*x3;
                a3 += w3.x*x0 + w3.y*x1 + w3.z*x2 + w3.w*x3;
            }
            ab[(r0+0)*VJ + v] = a0 + bias[0];
            ab[(r0+1)*VJ + v] = a1 + bias[1];
            ab[(r0+2)*VJ + v] = a2 + bias[2];
            ab[(r0+3)*VJ + v] = a3 + bias[3];
        }
        __syncthreads();
        int p = 0;
        for (int e = tid; e < 625; e += 256, ++p) {
            int u = e / 25, w = e % 25;
            float s = 0.f;
            #pragma unroll
            for (int o = 0; o < 16; ++o)
                s += ab[o*VJ + u] * ab[(16+o)*VJ + w];
            Mloc[p] += s;
        }
    }
    int p = 0;
    for (int e = tid; e < 625; e += 256, ++p)
        atomicAdd(&Mbuf[(i*NB + n)*625 + e], Mloc[p]);
}

// ---------------- column softmax + A+PA ----------------
__global__ void k_softmax(const float* __restrict__ A, const float* __restrict__ PA,
                          float* __restrict__ Mbuf) {
    int b = blockIdx.x;
    int i = b / NB;
    int w = threadIdx.x;
    if (w >= 25) return;
    float* M = Mbuf + b*625;
    const float scale = 1.0f / (float)(ICB * TF);
    float col[25];
    float mx = -1e30f;
    #pragma unroll
    for (int u = 0; u < 25; ++u) { col[u] = M[u*25 + w] * scale; mx = fmaxf(mx, col[u]); }
    float s = 0.f;
    #pragma unroll
    for (int u = 0; u < 25; ++u) { col[u] = __expf(col[u] - mx); s += col[u]; }
    float inv = 1.0f / s;
    #pragma unroll
    for (int u = 0; u < 25; ++u)
        M[u*25 + w] = col[u]*inv + A[i*625 + u*25 + w] + PA[i*625 + u*25 + w];
}

// ---------------- y = sum_i Wd_i @ (x @ attn_i) + bd ----------------
__global__ __launch_bounds__(256) void k_y(
    const float* __restrict__ x, const float* __restrict__ attn,
    const float* __restrict__ Wd, const float* __restrict__ bd,
    float* __restrict__ ybuf)
{
    __shared__ __align__(16) float xs[CH*4*28];
    __shared__ __align__(16) float zs[CH*100];
    __shared__ __align__(16) float wdT[CH*CH];
    __shared__ __align__(16) float atT[25*28];

    int b = blockIdx.x;
    int n = b / 75, tt = b % 75;
    int t0 = tt * 4;
    int tid = threadIdx.x;
    int ty = tid >> 4, tx = tid & 15;
    int o0 = ty * 4;

    const float* xg = x + (long)n*CTVsz + t0*VJ;
    for (int e = tid; e < CH*100; e += 256) {
        int c = e / 100, tv = e % 100;
        int tq = tv / 25, u = tv % 25;
        xs[(c*4 + tq)*28 + u] = xg[c*TVsz + tv];
    }

    float acc[4][7];
    #pragma unroll
    for (int rr = 0; rr < 4; ++rr)
        #pragma unroll
        for (int j = 0; j < 7; ++j) acc[rr][j] = 0.f;

    for (int i = 0; i < NSUB; ++i) {
        __syncthreads();
        for (int e = tid; e < CH*CH; e += 256) {
            int c = e >> 6, o = e & 63;
            wdT[e] = Wd[i*CH*CH + o*CH + c];
        }
        for (int e = tid; e < 625; e += 256) {
            int vv = e / 25, u = e % 25;
            atT[vv*28 + u] = attn[(i*NB + n)*625 + u*25 + vv];
        }
        __syncthreads();
        for (int e = tid; e < CH*VJ; e += 256) {
            int c = e / 25, vv = e % 25;
            const float* xc = &xs[c*4*28];
            const float* at = &atT[vv*28];
            float z0=0.f, z1=0.f, z2=0.f, z3=0.f;
            #pragma unroll
            for (int u = 0; u < 24; u += 4) {
                float4 a4 = *(const float4*)&at[u];
                float4 p0 = *(const float4*)&xc[0*28 + u];
                float4 p1 = *(const float4*)&xc[1*28 + u];
                float4 p2 = *(const float4*)&xc[2*28 + u];
                float4 p3 = *(const float4*)&xc[3*28 + u];
                z0 += a4.x*p0.x + a4.y*p0.y + a4.z*p0.z + a4.w*p0.w;
                z1 += a4.x*p1.x + a4.y*p1.y + a4.z*p1.z + a4.w*p1.w;
                z2 += a4.x*p2.x + a4.y*p2.y + a4.z*p2.z + a4.w*p2.w;
                z3 += a4.x*p3.x + a4.y*p3.y + a4.z*p3.z + a4.w*p3.w;
            }
            float a24 = at[24];
            z0 += a24*xc[0*28+24]; z1 += a24*xc[1*28+24];
            z2 += a24*xc[2*28+24]; z3 += a24*xc[3*28+24];
            zs[c*100 + 0*25 + vv] = z0;
            zs[c*100 + 1*25 + vv] = z1;
            zs[c*100 + 2*25 + vv] = z2;
            zs[c*100 + 3*25 + vv] = z3;
        }
        __syncthreads();
        for (int c = 0; c < CH; ++c) {
            float4 w4 = *(const float4*)&wdT[c*CH + o0];
            #pragma unroll
            for (int j = 0; j < 7; ++j) {
                int tv = tx + 16*j;
                if (tv < 100) {
                    float zv = zs[c*100 + tv];
                    acc[0][j] += w4.x*zv;
                    acc[1][j] += w4.y*zv;
                    acc[2][j] += w4.z*zv;
                    acc[3][j] += w4.w*zv;
                }
            }
        }
    }

    float bds[4];
    #pragma unroll
    for (int rr = 0; rr < 4; ++rr)
        bds[rr] = bd[o0+rr] + bd[CH + o0+rr] + bd[2*CH + o0+rr];

    float* yg = ybuf + (long)n*CTVsz + t0*VJ;
    #pragma unroll
    for (int rr = 0; rr < 4; ++rr)
        #pragma unroll
        for (int j = 0; j < 7; ++j) {
            int tv = tx + 16*j;
            if (tv < 100) yg[(o0+rr)*TVsz + tv] = acc[rr][j] + bds[rr];
        }
}

// ---------------- per-channel sum/sumsq (f32 src) ----------------
__global__ __launch_bounds__(256) void k_bnstats(const float* __restrict__ src,
                                                 float* __restrict__ s1, float* __restrict__ s2) {
    int nc = blockIdx.x;
    int c = nc & 63;
    const float* p = src + (long)nc * TVsz;
    float s = 0.f, q = 0.f;
    for (int e = threadIdx.x; e < TVsz; e += 256) {
        float v = p[e];
        s += v; q += v*v;
    }
    #pragma unroll
    for (int off = 32; off; off >>= 1) {
        s += __shfl_down(s, off, 64);
        q += __shfl_down(q, off, 64);
    }
    __shared__ float rs[4], rq[4];
    int wid = threadIdx.x >> 6, lane = threadIdx.x & 63;
    if (lane == 0) { rs[wid] = s; rq[wid] = q; }
    __syncthreads();
    if (threadIdx.x == 0) {
        atomicAdd(s1 + c, rs[0]+rs[1]+rs[2]+rs[3]);
        atomicAdd(s2 + c, rq[0]+rq[1]+rq[2]+rq[3]);
    }
}

// ---------------- per-channel sum/sumsq (bf16 src, [n][c][tv]) ----------------
__global__ __launch_bounds__(256) void k_bnstats_bf(const unsigned short* __restrict__ src,
                                                    float* __restrict__ s1, float* __restrict__ s2) {
    int nc = blockIdx.x;
    int c = nc & 63;
    const uint2* p = (const uint2*)(src + (long)nc * TVsz);
    float s = 0.f, q = 0.f;
    for (int e = threadIdx.x; e < TVsz/4; e += 256) {
        uint2 d = p[e];
        float v0 = bf2f(d.x & 0xffffu), v1 = bf2f(d.x >> 16);
        float v2 = bf2f(d.y & 0xffffu), v3 = bf2f(d.y >> 16);
        s += (v0+v1) + (v2+v3);
        q += (v0*v0+v1*v1) + (v2*v2+v3*v3);
    }
    #pragma unroll
    for (int off = 32; off; off >>= 1) {
        s += __shfl_down(s, off, 64);
        q += __shfl_down(q, off, 64);
    }
    __shared__ float rs[4], rq[4];
    int wid = threadIdx.x >> 6, lane = threadIdx.x & 63;
    if (lane == 0) { rs[wid] = s; rq[wid] = q; }
    __syncthreads();
    if (threadIdx.x == 0) {
        atomicAdd(s1 + c, rs[0]+rs[1]+rs[2]+rs[3]);
        atomicAdd(s2 + c, rq[0]+rq[1]+rq[2]+rq[3]);
    }
}

// ---------------- y = relu(bn1(y)+x) -> bf16 transposed [n][tv][c] ----------------
__global__ __launch_bounds__(256) void k_bn1t(
    const float* __restrict__ x, const float* __restrict__ g1, const float* __restrict__ b1,
    const float* __restrict__ s1, const float* __restrict__ s2,
    const float* __restrict__ yb, unsigned short* __restrict__ ybt)
{
    __shared__ unsigned short ls[64*66];   // pad 66: row stride 132B -> conflict-free col writes
    int b = blockIdx.x;
    int n = b / 118, tile = b % 118;
    int tv0 = tile * 64;
    const float invN = 1.0f / (float)PCCOUNT;
    int tid = threadIdx.x;

    for (int e = tid; e < 4096; e += 256) {
        int c = e >> 6, tvl = e & 63;
        int tv = tv0 + tvl;
        unsigned short hv = 0;
        if (tv < TVsz) {
            long gi = (long)n*CTVsz + (long)c*TVsz + tv;
            float m  = s1[c] * invN;
            float vr = s2[c] * invN - m*m;
            float val = (yb[gi] - m) * rsqrtf(vr + EPSB) * g1[c] + b1[c] + x[gi];
            hv = f2bf(fmaxf(val, 0.f));
        }
        ls[tvl*66 + c] = hv;
    }
    __syncthreads();
    for (int e = tid; e < 1024; e += 256) {
        int tvl = e >> 4, c4 = (e & 15) * 4;
        int tv = tv0 + tvl;
        if (tv < TVsz) {
            unsigned int lo = *(const unsigned int*)&ls[tvl*66 + c4];
            unsigned int hi = *(const unsigned int*)&ls[tvl*66 + c4 + 2];
            *(uint2*)&ybt[((long)n*TVsz + tv)*CH + c4] = make_uint2(lo, hi);
        }
    }
}

// ---------------- temporal conv via MFMA: yc_bf16 = conv(y_bf16) + bt ----------------
#define NTILE 256
#define HALO 100
#define ROWS 456   // NTILE + 2*HALO

__global__ __launch_bounds__(256) void k_tconv(
    const unsigned short* __restrict__ ybt, const unsigned short* __restrict__ awT,
    const float* __restrict__ bt, unsigned short* __restrict__ ycb)
{
    __shared__ __align__(16) char ys[ROWS*128];   // [row][c] bf16, XOR-swizzled 16B granule
    int b = blockIdx.x;
    int n = b / 30, tile = b % 30;
    int tv0 = tile * NTILE;
    int tid = threadIdx.x;

    const char* src = (const char*)(ybt + (long)n * TVsz * CH);
    for (int q = tid; q < ROWS*16; q += 256) {
        int row = q >> 4;
        int cb  = (q & 15) << 3;
        int tvg = tv0 - HALO + row;
        uint2 val = make_uint2(0u, 0u);
        if (tvg >= 0 && tvg < TVsz)
            val = *(const uint2*)(src + (long)tvg*128 + cb);
        *(uint2*)(ys + row*128 + (cb ^ ((row & 7) << 4))) = val;
    }
    __syncthreads();

    int wv = tid >> 6, l = tid & 63;
    int l15 = l & 15, lhi = l >> 4;

    f32x4 acc[4][4];
    #pragma unroll
    for (int mf = 0; mf < 4; ++mf)
        #pragma unroll
        for (int nf = 0; nf < 4; ++nf)
            acc[mf][nf] = (f32x4){0.f, 0.f, 0.f, 0.f};

    const short* aw = (const short*)awT;
    for (int tap = 0; tap < KW; ++tap) {
        #pragma unroll
        for (int kc = 0; kc < 2; ++kc) {
            s16x8 af[4], bfr[4];
            #pragma unroll
            for (int mf = 0; mf < 4; ++mf)
                af[mf] = *(const s16x8*)(aw + ((tap*CH + mf*16 + l15)*CH + kc*32 + lhi*8));
            #pragma unroll
            for (int nf = 0; nf < 4; ++nf) {
                int row = wv*64 + nf*16 + l15 + tap*25;
                int cb  = (kc*64 + lhi*16) ^ ((row & 7) << 4);
                bfr[nf] = *(const s16x8*)(ys + row*128 + cb);
            }
            #pragma unroll
            for (int mf = 0; mf < 4; ++mf)
                #pragma unroll
                for (int nf = 0; nf < 4; ++nf)
                    acc[mf][nf] = __builtin_amdgcn_mfma_f32_16x16x32_bf16(
                        af[mf], bfr[nf], acc[mf][nf], 0, 0, 0);
        }
    }

    #pragma unroll
    for (int mf = 0; mf < 4; ++mf) {
        #pragma unroll
        for (int nf = 0; nf < 4; ++nf) {
            int tv = tv0 + wv*64 + nf*16 + l15;
            if (tv < TVsz) {
                #pragma unroll
                for (int r = 0; r < 4; ++r) {
                    int o = mf*16 + lhi*4 + r;
                    float v = acc[mf][nf][r] + bt[o];
                    ycb[((long)n*CH + o)*TVsz + tv] = f2bf(v);
                }
            }
        }
    }
}

// ---------------- out = relu(bn2(yc)+x), f32, vectorized x4 ----------------
__global__ void k_out(const float* __restrict__ x, const float* __restrict__ g2, const float* __restrict__ b2,
                      const float* __restrict__ s1, const float* __restrict__ s2,
                      const unsigned short* __restrict__ ycb, float* __restrict__ out) {
    const float invN = 1.0f / (float)PCCOUNT;
    int stride = gridDim.x * blockDim.x;
    for (int i4 = blockIdx.x*blockDim.x + threadIdx.x; i4 < TOTAL/4; i4 += stride) {
        long idx = (long)i4 * 4;
        int c = (int)((idx / TVsz) & 63);
        float m  = s1[c] * invN;
        float vr = s2[c] * invN - m*m;
        float rs = rsqrtf(vr + EPSB) * g2[c];
        float bc = b2[c];
        uint2 d = *(const uint2*)(ycb + idx);
        float4 xv = *(const float4*)(x + idx);
        float4 ov;
        ov.x = fmaxf((bf2f(d.x & 0xffffu) - m)*rs + bc + xv.x, 0.f);
        ov.y = fmaxf((bf2f(d.x >> 16)     - m)*rs + bc + xv.y, 0.f);
        ov.z = fmaxf((bf2f(d.y & 0xffffu) - m)*rs + bc + xv.z, 0.f);
        ov.w = fmaxf((bf2f(d.y >> 16)     - m)*rs + bc + xv.w, 0.f);
        *(float4*)(out + idx) = ov;
    }
}

extern "C" void kernel_launch(void* const* d_in, const int* in_sizes, int n_in,
                              void* d_out, int out_size, void* d_ws, size_t ws_size,
                              hipStream_t stream) {
    const float* x  = (const float*)d_in[0];
    const float* A  = (const float*)d_in[1];
    const float* PA = (const float*)d_in[2];
    const float* Wa = (const float*)d_in[3];
    const float* ba = (const float*)d_in[4];
    const float* Wb = (const float*)d_in[5];
    const float* bb = (const float*)d_in[6];
    const float* Wd = (const float*)d_in[7];
    const float* bd = (const float*)d_in[8];
    const float* g1 = (const float*)d_in[9];
    const float* b1 = (const float*)d_in[10];
    const float* Wt = (const float*)d_in[11];
    const float* bt = (const float*)d_in[12];
    const float* g2 = (const float*)d_in[13];
    const float* b2 = (const float*)d_in[14];

    float* ws    = (float*)d_ws;
    float* Mbuf  = ws;                                   // 60000 f32
    float* stats = ws + 60000;                           // 256 f32
    float* ybuf  = ws + 60256;                           // 15360000 f32
    unsigned short* ybt = (unsigned short*)(ybuf + TOTAL);   // 15360000 bf16 [n][tv][c]
    unsigned short* ycb = ybt + TOTAL;                   // 15360000 bf16 [n][c][tv]
    unsigned short* awT = ycb + TOTAL;                   // 36864 bf16

    hipMemsetAsync(Mbuf, 0, (60000 + 256)*sizeof(float), stream);
    k_wtT<<<(CH*CH*KW + 255)/256, 256, 0, stream>>>(Wt, awT);
    k_attn_partial<<<NSUB*NB*TCHUNK, 256, 0, stream>>>(x, Wa, ba, Wb, bb, Mbuf);
    k_softmax<<<NSUB*NB, 32, 0, stream>>>(A, PA, Mbuf);
    k_y<<<NB*75, 256, 0, stream>>>(x, Mbuf, Wd, bd, ybuf);
    k_bnstats<<<NB*CH, 256, 0, stream>>>(ybuf, stats, stats + 64);
    k_bn1t<<<NB*118, 256, 0, stream>>>(x, g1, b1, stats, stats + 64, ybuf, ybt);
    k_tconv<<<NB*30, 256, 0, stream>>>(ybt, awT, bt, ycb);
    k_bnstats_bf<<<NB*CH, 256, 0, stream>>>(ycb, stats + 128, stats + 192);
    k_out<<<2048, 256, 0, stream>>>(x, g2, b2, stats + 128, stats + 192, ycb, (float*)d_out);
}

// Round 3
// 541.520 us; speedup vs baseline: 2.7712x; 1.1300x over previous
//
#include <hip/hip_runtime.h>
#include <hip/hip_bf16.h>

#define NB 32
#define CH 64
#define TF 300
#define VJ 25
#define NSUB 3
#define ICB 16
#define KW 9
#define EPSB 1e-5f

#define TVsz (TF*VJ)          // 7500
#define CTVsz (CH*TF*VJ)      // 480000
#define TOTAL (NB*CTVsz)      // 15360000
#define PCCOUNT (NB*TF*VJ)    // 240000

#define TCHUNK 10
#define TCLEN 30

#define NCHUNK 8              // n per chunk
#define NTILES 59             // ceil(7500/128) for k_g

typedef __attribute__((ext_vector_type(8))) short s16x8;
typedef __attribute__((ext_vector_type(4))) float f32x4;

__device__ __forceinline__ unsigned short f2bf(float v) {
    __hip_bfloat16 h = __float2bfloat16(v);
    return *(unsigned short*)&h;
}
__device__ __forceinline__ float bf2f(unsigned int u) {
    return __uint_as_float(u << 16);
}

// ---------------- Wt repack: [o][c][k] f32 -> [k][o][c] bf16 ----------------
__global__ void k_wtT(const float* __restrict__ Wt, unsigned short* __restrict__ awT) {
    int e = blockIdx.x * 256 + threadIdx.x;
    if (e >= CH*CH*KW) return;
    int o = e / (CH*KW);
    int c = (e / KW) % CH;
    int k = e % KW;
    awT[(k*CH + o)*CH + c] = f2bf(Wt[e]);
}

// ---------------- Wd repack: [i][o][c] f32 -> [i*64+o][c] bf16 ----------------
__global__ void k_wpack(const float* __restrict__ Wd, unsigned short* __restrict__ wdcat) {
    int e = blockIdx.x * 256 + threadIdx.x;
    if (e >= NSUB*CH*CH) return;
    wdcat[e] = f2bf(Wd[e]);
}

// ---------------- x transpose chunk: [8n][c][tv] f32 -> [8n][tv][c] bf16 ----
__global__ __launch_bounds__(256) void k_xt(const float* __restrict__ xc,
                                            unsigned short* __restrict__ xbt) {
    __shared__ unsigned short ls[64*66];
    int b = blockIdx.x;
    int nc = b / 118, tile = b % 118;
    int tv0 = tile * 64;
    int tid = threadIdx.x;
    const float* xg = xc + (long)nc * CTVsz;
    for (int e = tid; e < 4096; e += 256) {
        int c = e >> 6, tvl = e & 63;
        int tv = tv0 + tvl;
        unsigned short hv = 0;
        if (tv < TVsz) hv = f2bf(xg[(long)c*TVsz + tv]);
        ls[tvl*66 + c] = hv;
    }
    __syncthreads();
    for (int e = tid; e < 1024; e += 256) {
        int tvl = e >> 4, c4 = (e & 15) * 4;
        int tv = tv0 + tvl;
        if (tv < TVsz) {
            unsigned int lo = *(const unsigned int*)&ls[tvl*66 + c4];
            unsigned int hi = *(const unsigned int*)&ls[tvl*66 + c4 + 2];
            *(uint2*)&xbt[((long)nc*TVsz + tv)*CH + c4] = make_uint2(lo, hi);
        }
    }
}

// ---------------- GEMM1: g = Wdcat[192,64] x[64,7500] per n (chunk) --------
// g layout: [nc][m=i*64+o][t][32] bf16, u in [0,25) data, [25,32) zeroed
__global__ __launch_bounds__(256) void k_g(const unsigned short* __restrict__ xbt,
                                           const unsigned short* __restrict__ wdcat,
                                           unsigned short* __restrict__ g) {
    int b = blockIdx.x;
    int nc = b / NTILES, tile = b % NTILES;
    int tv0 = tile * 128;
    int tid = threadIdx.x;
    int w = tid >> 6, wm = w >> 1, wn = w & 1;
    int l = tid & 63, l15 = l & 15, lhi = l >> 4;

    s16x8 af[6][2];
    #pragma unroll
    for (int mf = 0; mf < 6; ++mf)
        #pragma unroll
        for (int kc = 0; kc < 2; ++kc)
            af[mf][kc] = *(const s16x8*)(wdcat + ((wm*96 + mf*16 + l15)*64 + kc*32 + lhi*8));

    f32x4 acc[6][4];
    #pragma unroll
    for (int mf = 0; mf < 6; ++mf)
        #pragma unroll
        for (int nf = 0; nf < 4; ++nf)
            acc[mf][nf] = (f32x4){0.f,0.f,0.f,0.f};

    const unsigned short* xb = xbt + (long)nc * TVsz * CH;
    #pragma unroll
    for (int nf = 0; nf < 4; ++nf) {
        int tv = tv0 + wn*64 + nf*16 + l15;
        int tvc = tv < TVsz ? tv : TVsz-1;
        s16x8 b0 = *(const s16x8*)(xb + (long)tvc*CH + lhi*8);
        s16x8 b1 = *(const s16x8*)(xb + (long)tvc*CH + 32 + lhi*8);
        #pragma unroll
        for (int mf = 0; mf < 6; ++mf) {
            acc[mf][nf] = __builtin_amdgcn_mfma_f32_16x16x32_bf16(af[mf][0], b0, acc[mf][nf], 0,0,0);
            acc[mf][nf] = __builtin_amdgcn_mfma_f32_16x16x32_bf16(af[mf][1], b1, acc[mf][nf], 0,0,0);
        }
    }

    #pragma unroll
    for (int nf = 0; nf < 4; ++nf) {
        int tv = tv0 + wn*64 + nf*16 + l15;
        if (tv < TVsz) {
            int t = tv / 25, u = tv % 25;
            #pragma unroll
            for (int mf = 0; mf < 6; ++mf) {
                #pragma unroll
                for (int r = 0; r < 4; ++r) {
                    int m = wm*96 + mf*16 + lhi*4 + r;
                    long base = (((long)nc*192 + m)*TF + t)*32;
                    g[base + u] = f2bf(acc[mf][nf][r]);
                    if (u == 24) {
                        #pragma unroll
                        for (int p = 25; p < 32; ++p) g[base + p] = 0;
                    }
                }
            }
        }
    }
}

// ---------------- GEMM2: y[o,t,v] = sum_{i,u} g[(i,o),t,u] attn_i[u,v] + bd ----
__global__ __launch_bounds__(256) void k_y2(const unsigned short* __restrict__ g,
                                            const float* __restrict__ Mbuf,
                                            const float* __restrict__ bd,
                                            float* __restrict__ ybuf, int n0) {
    __shared__ unsigned short attnT[32][104];   // [v][i*32+u], pad 104 -> 2-way only
    int b = blockIdx.x;
    int nc = b / 320;
    int rem = b % 320;
    int o = rem / 5, tb = rem % 5;
    int n = n0 + nc;
    int tid = threadIdx.x;

    for (int e = tid; e < 32*104; e += 256) ((unsigned short*)attnT)[e] = 0;
    __syncthreads();
    for (int e = tid; e < 3*625; e += 256) {
        int i = e / 625, uw = e % 625;
        int u = uw / 25, v = uw % 25;
        attnT[v][i*32 + u] = f2bf(Mbuf[(i*NB + n)*625 + uw]);
    }
    __syncthreads();

    int w = tid >> 6, l = tid & 63, l15 = l & 15, lhi = l >> 4;
    int t0 = tb*64 + w*16;

    f32x4 acc[2];
    acc[0] = (f32x4){0.f,0.f,0.f,0.f};
    acc[1] = (f32x4){0.f,0.f,0.f,0.f};

    #pragma unroll
    for (int kc = 0; kc < 3; ++kc) {
        int t = t0 + l15; if (t > 299) t = 299;
        s16x8 a = *(const s16x8*)(g + ((((long)nc*192 + kc*64 + o)*TF + t)*32 + lhi*8));
        #pragma unroll
        for (int nf = 0; nf < 2; ++nf) {
            s16x8 bfr = *(const s16x8*)(&attnT[nf*16 + l15][kc*32 + lhi*8]);
            acc[nf] = __builtin_amdgcn_mfma_f32_16x16x32_bf16(a, bfr, acc[nf], 0,0,0);
        }
    }

    float bds = bd[o] + bd[CH + o] + bd[2*CH + o];
    #pragma unroll
    for (int nf = 0; nf < 2; ++nf) {
        #pragma unroll
        for (int r = 0; r < 4; ++r) {
            int t = t0 + lhi*4 + r;
            int v = nf*16 + l15;
            if (t < TF && v < VJ)
                ybuf[((long)n*CH + o)*TVsz + t*25 + v] = acc[nf][r] + bds;
        }
    }
}

// ---------------- attention Gram partial ----------------
__global__ __launch_bounds__(256) void k_attn_partial(
    const float* __restrict__ x, const float* __restrict__ Wa, const float* __restrict__ ba,
    const float* __restrict__ Wb, const float* __restrict__ bb, float* __restrict__ Mbuf)
{
    __shared__ __align__(16) float xs[CH*VJ];
    __shared__ __align__(16) float Wab[32*CH];
    __shared__ __align__(16) float ab[32*VJ];

    int b = blockIdx.x;
    int i   = b / (NB*TCHUNK);
    int rem = b % (NB*TCHUNK);
    int n   = rem / TCHUNK;
    int tc  = rem % TCHUNK;
    int tid = threadIdx.x;

    for (int e = tid; e < 32*CH; e += 256) {
        int r = e >> 6, c = e & 63;
        Wab[e] = (r < 16) ? Wa[(i*ICB + r)*CH + c] : Wb[(i*ICB + (r-16))*CH + c];
    }

    int v = tid % 25, g = tid / 25;
    bool act = (tid < 200);
    int r0 = g * 4;
    float bias[4];
    if (act) {
        #pragma unroll
        for (int rr = 0; rr < 4; ++rr) {
            int r = r0 + rr;
            bias[rr] = (r < 16) ? ba[i*ICB + r] : bb[i*ICB + (r-16)];
        }
    }

    float Mloc[3] = {0.f, 0.f, 0.f};
    const float* xg = x + (long)n * CTVsz;

    for (int t = tc*TCLEN; t < tc*TCLEN + TCLEN; ++t) {
        __syncthreads();
        for (int e = tid; e < CH*VJ; e += 256) {
            int c = e / 25, vv = e % 25;
            xs[e] = xg[c*TVsz + t*VJ + vv];
        }
        __syncthreads();
        if (act) {
            float a0=0.f, a1=0.f, a2=0.f, a3=0.f;
            #pragma unroll
            for (int c = 0; c < CH; c += 4) {
                float x0 = xs[(c+0)*VJ + v];
                float x1 = xs[(c+1)*VJ + v];
                float x2 = xs[(c+2)*VJ + v];
                float x3 = xs[(c+3)*VJ + v];
                float4 w0 = *(const float4*)&Wab[(r0+0)*CH + c];
                float4 w1 = *(const float4*)&Wab[(r0+1)*CH + c];
                float4 w2 = *(const float4*)&Wab[(r0+2)*CH + c];
                float4 w3 = *(const float4*)&Wab[(r0+3)*CH + c];
                a0 += w0.x*x0 + w0.y*x1 + w0.z*x2 + w0.w*x3;
                a1 += w1.x*x0 + w1.y*x1 + w1.z*x2 + w1.w*x3;
                a2 += w2.x*x0 + w2.y*x1 + w2.z*x2 + w2.w*x3;
                a3 += w3.x*x0 + w3.y*x1 + w3.z*x2 + w3.w*x3;
            }
            ab[(r0+0)*VJ + v] = a0 + bias[0];
            ab[(r0+1)*VJ + v] = a1 + bias[1];
            ab[(r0+2)*VJ + v] = a2 + bias[2];
            ab[(r0+3)*VJ + v] = a3 + bias[3];
        }
        __syncthreads();
        int p = 0;
        for (int e = tid; e < 625; e += 256, ++p) {
            int u = e / 25, w = e % 25;
            float s = 0.f;
            #pragma unroll
            for (int o = 0; o < 16; ++o)
                s += ab[o*VJ + u] * ab[(16+o)*VJ + w];
            Mloc[p] += s;
        }
    }
    int p = 0;
    for (int e = tid; e < 625; e += 256, ++p)
        atomicAdd(&Mbuf[(i*NB + n)*625 + e], Mloc[p]);
}

// ---------------- column softmax + A+PA ----------------
__global__ void k_softmax(const float* __restrict__ A, const float* __restrict__ PA,
                          float* __restrict__ Mbuf) {
    int b = blockIdx.x;
    int i = b / NB;
    int w = threadIdx.x;
    if (w >= 25) return;
    float* M = Mbuf + b*625;
    const float scale = 1.0f / (float)(ICB * TF);
    float col[25];
    float mx = -1e30f;
    #pragma unroll
    for (int u = 0; u < 25; ++u) { col[u] = M[u*25 + w] * scale; mx = fmaxf(mx, col[u]); }
    float s = 0.f;
    #pragma unroll
    for (int u = 0; u < 25; ++u) { col[u] = __expf(col[u] - mx); s += col[u]; }
    float inv = 1.0f / s;
    #pragma unroll
    for (int u = 0; u < 25; ++u)
        M[u*25 + w] = col[u]*inv + A[i*625 + u*25 + w] + PA[i*625 + u*25 + w];
}

// ---------------- per-channel sum/sumsq (f32 src) ----------------
__global__ __launch_bounds__(256) void k_bnstats(const float* __restrict__ src,
                                                 float* __restrict__ s1, float* __restrict__ s2) {
    int nc = blockIdx.x;
    int c = nc & 63;
    const float* p = src + (long)nc * TVsz;
    float s = 0.f, q = 0.f;
    for (int e = threadIdx.x; e < TVsz; e += 256) {
        float v = p[e];
        s += v; q += v*v;
    }
    #pragma unroll
    for (int off = 32; off; off >>= 1) {
        s += __shfl_down(s, off, 64);
        q += __shfl_down(q, off, 64);
    }
    __shared__ float rs[4], rq[4];
    int wid = threadIdx.x >> 6, lane = threadIdx.x & 63;
    if (lane == 0) { rs[wid] = s; rq[wid] = q; }
    __syncthreads();
    if (threadIdx.x == 0) {
        atomicAdd(s1 + c, rs[0]+rs[1]+rs[2]+rs[3]);
        atomicAdd(s2 + c, rq[0]+rq[1]+rq[2]+rq[3]);
    }
}

// ---------------- per-channel sum/sumsq (bf16 src, [n][c][tv]) ----------------
__global__ __launch_bounds__(256) void k_bnstats_bf(const unsigned short* __restrict__ src,
                                                    float* __restrict__ s1, float* __restrict__ s2) {
    int nc = blockIdx.x;
    int c = nc & 63;
    const uint2* p = (const uint2*)(src + (long)nc * TVsz);
    float s = 0.f, q = 0.f;
    for (int e = threadIdx.x; e < TVsz/4; e += 256) {
        uint2 d = p[e];
        float v0 = bf2f(d.x & 0xffffu), v1 = bf2f(d.x >> 16);
        float v2 = bf2f(d.y & 0xffffu), v3 = bf2f(d.y >> 16);
        s += (v0+v1) + (v2+v3);
        q += (v0*v0+v1*v1) + (v2*v2+v3*v3);
    }
    #pragma unroll
    for (int off = 32; off; off >>= 1) {
        s += __shfl_down(s, off, 64);
        q += __shfl_down(q, off, 64);
    }
    __shared__ float rs[4], rq[4];
    int wid = threadIdx.x >> 6, lane = threadIdx.x & 63;
    if (lane == 0) { rs[wid] = s; rq[wid] = q; }
    __syncthreads();
    if (threadIdx.x == 0) {
        atomicAdd(s1 + c, rs[0]+rs[1]+rs[2]+rs[3]);
        atomicAdd(s2 + c, rq[0]+rq[1]+rq[2]+rq[3]);
    }
}

// ---------------- y = relu(bn1(y)+x) -> bf16 transposed [n][tv][c] ----------------
__global__ __launch_bounds__(256) void k_bn1t(
    const float* __restrict__ x, const float* __restrict__ g1, const float* __restrict__ b1,
    const float* __restrict__ s1, const float* __restrict__ s2,
    const float* __restrict__ yb, unsigned short* __restrict__ ybt)
{
    __shared__ unsigned short ls[64*66];
    int b = blockIdx.x;
    int n = b / 118, tile = b % 118;
    int tv0 = tile * 64;
    const float invN = 1.0f / (float)PCCOUNT;
    int tid = threadIdx.x;

    for (int e = tid; e < 4096; e += 256) {
        int c = e >> 6, tvl = e & 63;
        int tv = tv0 + tvl;
        unsigned short hv = 0;
        if (tv < TVsz) {
            long gi = (long)n*CTVsz + (long)c*TVsz + tv;
            float m  = s1[c] * invN;
            float vr = s2[c] * invN - m*m;
            float val = (yb[gi] - m) * rsqrtf(vr + EPSB) * g1[c] + b1[c] + x[gi];
            hv = f2bf(fmaxf(val, 0.f));
        }
        ls[tvl*66 + c] = hv;
    }
    __syncthreads();
    for (int e = tid; e < 1024; e += 256) {
        int tvl = e >> 4, c4 = (e & 15) * 4;
        int tv = tv0 + tvl;
        if (tv < TVsz) {
            unsigned int lo = *(const unsigned int*)&ls[tvl*66 + c4];
            unsigned int hi = *(const unsigned int*)&ls[tvl*66 + c4 + 2];
            *(uint2*)&ybt[((long)n*TVsz + tv)*CH + c4] = make_uint2(lo, hi);
        }
    }
}

// ---------------- temporal conv via MFMA ----------------
#define NTILE 256
#define HALO 100
#define ROWS 456

__global__ __launch_bounds__(256) void k_tconv(
    const unsigned short* __restrict__ ybt, const unsigned short* __restrict__ awT,
    const float* __restrict__ bt, unsigned short* __restrict__ ycb)
{
    __shared__ __align__(16) char ys[ROWS*128];
    int b = blockIdx.x;
    int n = b / 30, tile = b % 30;
    int tv0 = tile * NTILE;
    int tid = threadIdx.x;

    const char* src = (const char*)(ybt + (long)n * TVsz * CH);
    for (int q = tid; q < ROWS*16; q += 256) {
        int row = q >> 4;
        int cb  = (q & 15) << 3;
        int tvg = tv0 - HALO + row;
        uint2 val = make_uint2(0u, 0u);
        if (tvg >= 0 && tvg < TVsz)
            val = *(const uint2*)(src + (long)tvg*128 + cb);
        *(uint2*)(ys + row*128 + (cb ^ ((row & 7) << 4))) = val;
    }
    __syncthreads();

    int wv = tid >> 6, l = tid & 63;
    int l15 = l & 15, lhi = l >> 4;

    f32x4 acc[4][4];
    #pragma unroll
    for (int mf = 0; mf < 4; ++mf)
        #pragma unroll
        for (int nf = 0; nf < 4; ++nf)
            acc[mf][nf] = (f32x4){0.f, 0.f, 0.f, 0.f};

    const short* aw = (const short*)awT;
    for (int tap = 0; tap < KW; ++tap) {
        #pragma unroll
        for (int kc = 0; kc < 2; ++kc) {
            s16x8 af[4], bfr[4];
            #pragma unroll
            for (int mf = 0; mf < 4; ++mf)
                af[mf] = *(const s16x8*)(aw + ((tap*CH + mf*16 + l15)*CH + kc*32 + lhi*8));
            #pragma unroll
            for (int nf = 0; nf < 4; ++nf) {
                int row = wv*64 + nf*16 + l15 + tap*25;
                int cb  = (kc*64 + lhi*16) ^ ((row & 7) << 4);
                bfr[nf] = *(const s16x8*)(ys + row*128 + cb);
            }
            #pragma unroll
            for (int mf = 0; mf < 4; ++mf)
                #pragma unroll
                for (int nf = 0; nf < 4; ++nf)
                    acc[mf][nf] = __builtin_amdgcn_mfma_f32_16x16x32_bf16(
                        af[mf], bfr[nf], acc[mf][nf], 0, 0, 0);
        }
    }

    #pragma unroll
    for (int mf = 0; mf < 4; ++mf) {
        #pragma unroll
        for (int nf = 0; nf < 4; ++nf) {
            int tv = tv0 + wv*64 + nf*16 + l15;
            if (tv < TVsz) {
                #pragma unroll
                for (int r = 0; r < 4; ++r) {
                    int o = mf*16 + lhi*4 + r;
                    float v = acc[mf][nf][r] + bt[o];
                    ycb[((long)n*CH + o)*TVsz + tv] = f2bf(v);
                }
            }
        }
    }
}

// ---------------- out = relu(bn2(yc)+x), f32 ----------------
__global__ void k_out(const float* __restrict__ x, const float* __restrict__ g2, const float* __restrict__ b2,
                      const float* __restrict__ s1, const float* __restrict__ s2,
                      const unsigned short* __restrict__ ycb, float* __restrict__ out) {
    const float invN = 1.0f / (float)PCCOUNT;
    int stride = gridDim.x * blockDim.x;
    for (int i4 = blockIdx.x*blockDim.x + threadIdx.x; i4 < TOTAL/4; i4 += stride) {
        long idx = (long)i4 * 4;
        int c = (int)((idx / TVsz) & 63);
        float m  = s1[c] * invN;
        float vr = s2[c] * invN - m*m;
        float rs = rsqrtf(vr + EPSB) * g2[c];
        float bc = b2[c];
        uint2 d = *(const uint2*)(ycb + idx);
        float4 xv = *(const float4*)(x + idx);
        float4 ov;
        ov.x = fmaxf((bf2f(d.x & 0xffffu) - m)*rs + bc + xv.x, 0.f);
        ov.y = fmaxf((bf2f(d.x >> 16)     - m)*rs + bc + xv.y, 0.f);
        ov.z = fmaxf((bf2f(d.y & 0xffffu) - m)*rs + bc + xv.z, 0.f);
        ov.w = fmaxf((bf2f(d.y >> 16)     - m)*rs + bc + xv.w, 0.f);
        *(float4*)(out + idx) = ov;
    }
}

extern "C" void kernel_launch(void* const* d_in, const int* in_sizes, int n_in,
                              void* d_out, int out_size, void* d_ws, size_t ws_size,
                              hipStream_t stream) {
    const float* x  = (const float*)d_in[0];
    const float* A  = (const float*)d_in[1];
    const float* PA = (const float*)d_in[2];
    const float* Wa = (const float*)d_in[3];
    const float* ba = (const float*)d_in[4];
    const float* Wb = (const float*)d_in[5];
    const float* bb = (const float*)d_in[6];
    const float* Wd = (const float*)d_in[7];
    const float* bd = (const float*)d_in[8];
    const float* g1 = (const float*)d_in[9];
    const float* b1 = (const float*)d_in[10];
    const float* Wt = (const float*)d_in[11];
    const float* bt = (const float*)d_in[12];
    const float* g2 = (const float*)d_in[13];
    const float* b2 = (const float*)d_in[14];

    float* ws    = (float*)d_ws;
    float* Mbuf  = ws;                                       // 60000 f32
    float* stats = ws + 60000;                               // 256 f32
    unsigned short* wdcat = (unsigned short*)(ws + 60256);   // 12288 shorts = 6144 f32
    float* ybuf  = ws + 66400;                               // 15,360,000 f32
    float* R     = ws + 15426400;                            // reuse region
    // phase 1 (per chunk): xbt_c then g_c
    unsigned short* xbt_c = (unsigned short*)R;                       // 3,840,000 shorts
    unsigned short* g_c   = (unsigned short*)(R + 1920000);           // 14,745,600 shorts
    // phase 2: ybt, ycb, awT
    unsigned short* ybt = (unsigned short*)R;                         // 15,360,000 shorts
    unsigned short* ycb = (unsigned short*)(R + 7680000);             // 15,360,000 shorts
    unsigned short* awT = (unsigned short*)(R + 15360000);            // 36,864 shorts

    hipMemsetAsync(Mbuf, 0, (60000 + 256)*sizeof(float), stream);
    k_wpack<<<48, 256, 0, stream>>>(Wd, wdcat);
    k_attn_partial<<<NSUB*NB*TCHUNK, 256, 0, stream>>>(x, Wa, ba, Wb, bb, Mbuf);
    k_softmax<<<NSUB*NB, 32, 0, stream>>>(A, PA, Mbuf);

    for (int ch = 0; ch < 4; ++ch) {
        int n0 = ch * NCHUNK;
        k_xt<<<NCHUNK*118, 256, 0, stream>>>(x + (long)n0*CTVsz, xbt_c);
        k_g<<<NCHUNK*NTILES, 256, 0, stream>>>(xbt_c, wdcat, g_c);
        k_y2<<<NCHUNK*320, 256, 0, stream>>>(g_c, Mbuf, bd, ybuf, n0);
    }

    k_bnstats<<<NB*CH, 256, 0, stream>>>(ybuf, stats, stats + 64);
    k_bn1t<<<NB*118, 256, 0, stream>>>(x, g1, b1, stats, stats + 64, ybuf, ybt);
    k_wtT<<<(CH*CH*KW + 255)/256, 256, 0, stream>>>(Wt, awT);
    k_tconv<<<NB*30, 256, 0, stream>>>(ybt, awT, bt, ycb);
    k_bnstats_bf<<<NB*CH, 256, 0, stream>>>(ycb, stats + 128, stats + 192);
    k_out<<<2048, 256, 0, stream>>>(x, g2, b2, stats + 128, stats + 192, ycb, (float*)d_out);
}

// Round 4
// 358.569 us; speedup vs baseline: 4.1851x; 1.5102x over previous
//
#include <hip/hip_runtime.h>
#include <hip/hip_bf16.h>

#define NB 32
#define CH 64
#define TF 300
#define VJ 25
#define NSUB 3
#define ICB 16
#define KW 9
#define EPSB 1e-5f

#define TVsz (TF*VJ)          // 7500
#define CTVsz (CH*TF*VJ)      // 480000
#define TOTAL (NB*CTVsz)      // 15360000
#define PCCOUNT (NB*TF*VJ)    // 240000

#define NCHUNK 8              // n per chunk for g
#define NTILES 59             // ceil(7500/128) for k_g
#define ATC 32                // t per attention chunk
#define ATCN 10               // ceil(300/32)

typedef __attribute__((ext_vector_type(8))) short s16x8;
typedef __attribute__((ext_vector_type(4))) float f32x4;

__device__ __forceinline__ unsigned short f2bf(float v) {
    __hip_bfloat16 h = __float2bfloat16(v);
    return *(unsigned short*)&h;
}
__device__ __forceinline__ float bf2f(unsigned int u) {
    return __uint_as_float(u << 16);
}

// ---------------- Wt repack: [o][c][k] f32 -> [k][o][c] bf16 ----------------
__global__ void k_wtT(const float* __restrict__ Wt, unsigned short* __restrict__ awT) {
    int e = blockIdx.x * 256 + threadIdx.x;
    if (e >= CH*CH*KW) return;
    int o = e / (CH*KW);
    int c = (e / KW) % CH;
    int k = e % KW;
    awT[(k*CH + o)*CH + c] = f2bf(Wt[e]);
}

// ---------------- Wd repack: [i][o][c] f32 -> bf16 flat ----------------
__global__ void k_wpack(const float* __restrict__ Wd, unsigned short* __restrict__ wdcat) {
    int e = blockIdx.x * 256 + threadIdx.x;
    if (e >= NSUB*CH*CH) return;
    wdcat[e] = f2bf(Wd[e]);
}

// ---------------- Wa/Wb pack: [i][32 rows][64] bf16 + bias_cat[96] f32 ------
__global__ void k_wab(const float* __restrict__ Wa, const float* __restrict__ ba,
                      const float* __restrict__ Wb, const float* __restrict__ bb,
                      unsigned short* __restrict__ wcat, float* __restrict__ biascat) {
    int e = blockIdx.x * 256 + threadIdx.x;
    if (e < 6144) {
        int i = e / 2048, rm = (e >> 6) & 31, c = e & 63;
        float v = (rm < 16) ? Wa[(i*ICB + rm)*CH + c] : Wb[(i*ICB + rm - 16)*CH + c];
        wcat[e] = f2bf(v);
    } else if (e < 6240) {
        int j = e - 6144;
        int i = j >> 5, r = j & 31;
        biascat[j] = (r < 16) ? ba[i*ICB + r] : bb[i*ICB + r - 16];
    }
}

// ---------------- x transpose (all n): [n][c][tv] f32 -> [n][tv][c] bf16 ----
__global__ __launch_bounds__(256) void k_xt(const float* __restrict__ x,
                                            unsigned short* __restrict__ xbt) {
    __shared__ unsigned short ls[64*66];
    int b = blockIdx.x;
    int n = b / 118, tile = b % 118;
    int tv0 = tile * 64;
    int tid = threadIdx.x;
    const float* xg = x + (long)n * CTVsz;
    for (int e = tid; e < 4096; e += 256) {
        int c = e >> 6, tvl = e & 63;
        int tv = tv0 + tvl;
        unsigned short hv = 0;
        if (tv < TVsz) hv = f2bf(xg[(long)c*TVsz + tv]);
        ls[tvl*66 + c] = hv;
    }
    __syncthreads();
    for (int e = tid; e < 1024; e += 256) {
        int tvl = e >> 4, c4 = (e & 15) * 4;
        int tv = tv0 + tvl;
        if (tv < TVsz) {
            unsigned int lo = *(const unsigned int*)&ls[tvl*66 + c4];
            unsigned int hi = *(const unsigned int*)&ls[tvl*66 + c4 + 2];
            *(uint2*)&xbt[((long)n*TVsz + tv)*CH + c4] = make_uint2(lo, hi);
        }
    }
}

// ---------------- attention: emb MFMA -> LDS -> Gram MFMA -> atomics --------
// grid: NSUB * NB * ATCN = 960 blocks, 256 threads
__global__ __launch_bounds__(256) void k_attn(
    const unsigned short* __restrict__ xbt, const unsigned short* __restrict__ wcat,
    const float* __restrict__ biascat, float* __restrict__ Mbuf)
{
    __shared__ __align__(16) char emb[32*32*ATC*2];   // [v][m][tl] bf16, XOR-swizzled
    __shared__ float gram[625];
    int b = blockIdx.x;
    int i   = b / (NB*ATCN);
    int rem = b % (NB*ATCN);
    int n = rem / ATCN, tc = rem % ATCN;
    int t0 = tc * ATC;
    int tid = threadIdx.x;
    int wv = tid >> 6, l = tid & 63, l15 = l & 15, lhi = l >> 4;

    for (int e = tid; e < 625; e += 256) gram[e] = 0.f;

    s16x8 wf[2][2];
    #pragma unroll
    for (int mf = 0; mf < 2; ++mf)
        #pragma unroll
        for (int kc = 0; kc < 2; ++kc)
            wf[mf][kc] = *(const s16x8*)(wcat + ((i*32 + mf*16 + l15)*64 + kc*32 + lhi*8));
    float bs[2][4];
    #pragma unroll
    for (int mf = 0; mf < 2; ++mf)
        #pragma unroll
        for (int r = 0; r < 4; ++r)
            bs[mf][r] = biascat[i*32 + mf*16 + lhi*4 + r];

    // embedding GEMM: per v, emb[32 rows][t-chunk] = Wcat_i * x^T(:, :, v)
    const unsigned short* xb = xbt + (long)n * TVsz * CH;
    for (int v = wv; v < 25; v += 4) {
        f32x4 ae[2][2];
        #pragma unroll
        for (int mf = 0; mf < 2; ++mf)
            #pragma unroll
            for (int nf = 0; nf < 2; ++nf)
                ae[mf][nf] = (f32x4){0.f,0.f,0.f,0.f};
        #pragma unroll
        for (int nf = 0; nf < 2; ++nf) {
            int t = t0 + nf*16 + l15;
            int tcl = t < TF ? t : TF-1;
            const unsigned short* bp = xb + ((long)tcl*VJ + v)*CH;
            s16x8 b0 = *(const s16x8*)(bp + lhi*8);
            s16x8 b1 = *(const s16x8*)(bp + 32 + lhi*8);
            #pragma unroll
            for (int mf = 0; mf < 2; ++mf) {
                ae[mf][nf] = __builtin_amdgcn_mfma_f32_16x16x32_bf16(wf[mf][0], b0, ae[mf][nf], 0,0,0);
                ae[mf][nf] = __builtin_amdgcn_mfma_f32_16x16x32_bf16(wf[mf][1], b1, ae[mf][nf], 0,0,0);
            }
        }
        #pragma unroll
        for (int mf = 0; mf < 2; ++mf)
            #pragma unroll
            for (int nf = 0; nf < 2; ++nf)
                #pragma unroll
                for (int r = 0; r < 4; ++r) {
                    int t  = t0 + nf*16 + l15;
                    int tl = nf*16 + l15;
                    int m  = mf*16 + lhi*4 + r;
                    float val = (t < TF) ? (ae[mf][nf][r] + bs[mf][r]) : 0.f;
                    int byte = (((v*32 + m)*ATC + tl)*2) ^ ((v&7)<<4);
                    *(unsigned short*)(emb + byte) = f2bf(val);
                }
    }
    __syncthreads();

    // Gram: M[u,w] += sum_o sum_tl a[o,tl,u]*b[o,tl,w]; wave wv owns o = wv*4..+3
    f32x4 ag[2][2];
    #pragma unroll
    for (int mu = 0; mu < 2; ++mu)
        #pragma unroll
        for (int nw = 0; nw < 2; ++nw)
            ag[mu][nw] = (f32x4){0.f,0.f,0.f,0.f};
    #pragma unroll
    for (int oo = 0; oo < 4; ++oo) {
        int o = wv*4 + oo;
        s16x8 fa[2], fb[2];
        #pragma unroll
        for (int mu = 0; mu < 2; ++mu) {
            int u = mu*16 + l15; if (u > 24) u = 24;
            fa[mu] = *(const s16x8*)(emb + ((((u*32 + o)*ATC + lhi*8)*2) ^ ((u&7)<<4)));
        }
        #pragma unroll
        for (int nw = 0; nw < 2; ++nw) {
            int w = nw*16 + l15; if (w > 24) w = 24;
            fb[nw] = *(const s16x8*)(emb + ((((w*32 + 16 + o)*ATC + lhi*8)*2) ^ ((w&7)<<4)));
        }
        #pragma unroll
        for (int mu = 0; mu < 2; ++mu)
            #pragma unroll
            for (int nw = 0; nw < 2; ++nw)
                ag[mu][nw] = __builtin_amdgcn_mfma_f32_16x16x32_bf16(fa[mu], fb[nw], ag[mu][nw], 0,0,0);
    }
    #pragma unroll
    for (int mu = 0; mu < 2; ++mu)
        #pragma unroll
        for (int nw = 0; nw < 2; ++nw)
            #pragma unroll
            for (int r = 0; r < 4; ++r) {
                int u = mu*16 + lhi*4 + r;
                int w = nw*16 + l15;
                if (u < 25 && w < 25)
                    atomicAdd(&gram[u*25 + w], ag[mu][nw][r]);
            }
    __syncthreads();
    for (int e = tid; e < 625; e += 256)
        atomicAdd(&Mbuf[(i*NB + n)*625 + e], gram[e]);
}

// ---------------- column softmax + A+PA ----------------
__global__ void k_softmax(const float* __restrict__ A, const float* __restrict__ PA,
                          float* __restrict__ Mbuf) {
    int b = blockIdx.x;
    int i = b / NB;
    int w = threadIdx.x;
    if (w >= 25) return;
    float* M = Mbuf + b*625;
    const float scale = 1.0f / (float)(ICB * TF);
    float col[25];
    float mx = -1e30f;
    #pragma unroll
    for (int u = 0; u < 25; ++u) { col[u] = M[u*25 + w] * scale; mx = fmaxf(mx, col[u]); }
    float s = 0.f;
    #pragma unroll
    for (int u = 0; u < 25; ++u) { col[u] = __expf(col[u] - mx); s += col[u]; }
    float inv = 1.0f / s;
    #pragma unroll
    for (int u = 0; u < 25; ++u)
        M[u*25 + w] = col[u]*inv + A[i*625 + u*25 + w] + PA[i*625 + u*25 + w];
}

// ---------------- GEMM1: g = Wdcat[192,64] x[64,7500] per n (chunk) --------
__global__ __launch_bounds__(256) void k_g(const unsigned short* __restrict__ xbt,
                                           const unsigned short* __restrict__ wdcat,
                                           unsigned short* __restrict__ g) {
    int b = blockIdx.x;
    int nc = b / NTILES, tile = b % NTILES;
    int tv0 = tile * 128;
    int tid = threadIdx.x;
    int w = tid >> 6, wm = w >> 1, wn = w & 1;
    int l = tid & 63, l15 = l & 15, lhi = l >> 4;

    s16x8 af[6][2];
    #pragma unroll
    for (int mf = 0; mf < 6; ++mf)
        #pragma unroll
        for (int kc = 0; kc < 2; ++kc)
            af[mf][kc] = *(const s16x8*)(wdcat + ((wm*96 + mf*16 + l15)*64 + kc*32 + lhi*8));

    f32x4 acc[6][4];
    #pragma unroll
    for (int mf = 0; mf < 6; ++mf)
        #pragma unroll
        for (int nf = 0; nf < 4; ++nf)
            acc[mf][nf] = (f32x4){0.f,0.f,0.f,0.f};

    const unsigned short* xb = xbt + (long)nc * TVsz * CH;
    #pragma unroll
    for (int nf = 0; nf < 4; ++nf) {
        int tv = tv0 + wn*64 + nf*16 + l15;
        int tvc = tv < TVsz ? tv : TVsz-1;
        s16x8 b0 = *(const s16x8*)(xb + (long)tvc*CH + lhi*8);
        s16x8 b1 = *(const s16x8*)(xb + (long)tvc*CH + 32 + lhi*8);
        #pragma unroll
        for (int mf = 0; mf < 6; ++mf) {
            acc[mf][nf] = __builtin_amdgcn_mfma_f32_16x16x32_bf16(af[mf][0], b0, acc[mf][nf], 0,0,0);
            acc[mf][nf] = __builtin_amdgcn_mfma_f32_16x16x32_bf16(af[mf][1], b1, acc[mf][nf], 0,0,0);
        }
    }

    #pragma unroll
    for (int nf = 0; nf < 4; ++nf) {
        int tv = tv0 + wn*64 + nf*16 + l15;
        if (tv < TVsz) {
            int t = tv / 25, u = tv % 25;
            #pragma unroll
            for (int mf = 0; mf < 6; ++mf) {
                #pragma unroll
                for (int r = 0; r < 4; ++r) {
                    int m = wm*96 + mf*16 + lhi*4 + r;
                    long base = (((long)nc*192 + m)*TF + t)*32;
                    g[base + u] = f2bf(acc[mf][nf][r]);
                    if (u == 24) {
                        #pragma unroll
                        for (int p = 25; p < 32; ++p) g[base + p] = 0;
                    }
                }
            }
        }
    }
}

// ---------------- GEMM2: y[o,t,v] = sum_{i,u} g[(i,o),t,u] attn_i[u,v] + bd ----
__global__ __launch_bounds__(256) void k_y2(const unsigned short* __restrict__ g,
                                            const float* __restrict__ Mbuf,
                                            const float* __restrict__ bd,
                                            float* __restrict__ ybuf, int n0) {
    __shared__ unsigned short attnT[32][104];
    int b = blockIdx.x;
    int nc = b / 320;
    int rem = b % 320;
    int o = rem / 5, tb = rem % 5;
    int n = n0 + nc;
    int tid = threadIdx.x;

    for (int e = tid; e < 32*104; e += 256) ((unsigned short*)attnT)[e] = 0;
    __syncthreads();
    for (int e = tid; e < 3*625; e += 256) {
        int i = e / 625, uw = e % 625;
        int u = uw / 25, v = uw % 25;
        attnT[v][i*32 + u] = f2bf(Mbuf[(i*NB + n)*625 + uw]);
    }
    __syncthreads();

    int w = tid >> 6, l = tid & 63, l15 = l & 15, lhi = l >> 4;
    int t0 = tb*64 + w*16;

    f32x4 acc[2];
    acc[0] = (f32x4){0.f,0.f,0.f,0.f};
    acc[1] = (f32x4){0.f,0.f,0.f,0.f};

    #pragma unroll
    for (int kc = 0; kc < 3; ++kc) {
        int t = t0 + l15; if (t > 299) t = 299;
        s16x8 a = *(const s16x8*)(g + ((((long)nc*192 + kc*64 + o)*TF + t)*32 + lhi*8));
        #pragma unroll
        for (int nf = 0; nf < 2; ++nf) {
            s16x8 bfr = *(const s16x8*)(&attnT[nf*16 + l15][kc*32 + lhi*8]);
            acc[nf] = __builtin_amdgcn_mfma_f32_16x16x32_bf16(a, bfr, acc[nf], 0,0,0);
        }
    }

    float bds = bd[o] + bd[CH + o] + bd[2*CH + o];
    #pragma unroll
    for (int nf = 0; nf < 2; ++nf) {
        #pragma unroll
        for (int r = 0; r < 4; ++r) {
            int t = t0 + lhi*4 + r;
            int v = nf*16 + l15;
            if (t < TF && v < VJ)
                ybuf[((long)n*CH + o)*TVsz + t*25 + v] = acc[nf][r] + bds;
        }
    }
}

// ---------------- per-channel sum/sumsq (f32 src) ----------------
__global__ __launch_bounds__(256) void k_bnstats(const float* __restrict__ src,
                                                 float* __restrict__ s1, float* __restrict__ s2) {
    int nc = blockIdx.x;
    int c = nc & 63;
    const float* p = src + (long)nc * TVsz;
    float s = 0.f, q = 0.f;
    for (int e = threadIdx.x; e < TVsz; e += 256) {
        float v = p[e];
        s += v; q += v*v;
    }
    #pragma unroll
    for (int off = 32; off; off >>= 1) {
        s += __shfl_down(s, off, 64);
        q += __shfl_down(q, off, 64);
    }
    __shared__ float rs[4], rq[4];
    int wid = threadIdx.x >> 6, lane = threadIdx.x & 63;
    if (lane == 0) { rs[wid] = s; rq[wid] = q; }
    __syncthreads();
    if (threadIdx.x == 0) {
        atomicAdd(s1 + c, rs[0]+rs[1]+rs[2]+rs[3]);
        atomicAdd(s2 + c, rq[0]+rq[1]+rq[2]+rq[3]);
    }
}

// ---------------- per-channel sum/sumsq (bf16 src) ----------------
__global__ __launch_bounds__(256) void k_bnstats_bf(const unsigned short* __restrict__ src,
                                                    float* __restrict__ s1, float* __restrict__ s2) {
    int nc = blockIdx.x;
    int c = nc & 63;
    const uint2* p = (const uint2*)(src + (long)nc * TVsz);
    float s = 0.f, q = 0.f;
    for (int e = threadIdx.x; e < TVsz/4; e += 256) {
        uint2 d = p[e];
        float v0 = bf2f(d.x & 0xffffu), v1 = bf2f(d.x >> 16);
        float v2 = bf2f(d.y & 0xffffu), v3 = bf2f(d.y >> 16);
        s += (v0+v1) + (v2+v3);
        q += (v0*v0+v1*v1) + (v2*v2+v3*v3);
    }
    #pragma unroll
    for (int off = 32; off; off >>= 1) {
        s += __shfl_down(s, off, 64);
        q += __shfl_down(q, off, 64);
    }
    __shared__ float rs[4], rq[4];
    int wid = threadIdx.x >> 6, lane = threadIdx.x & 63;
    if (lane == 0) { rs[wid] = s; rq[wid] = q; }
    __syncthreads();
    if (threadIdx.x == 0) {
        atomicAdd(s1 + c, rs[0]+rs[1]+rs[2]+rs[3]);
        atomicAdd(s2 + c, rq[0]+rq[1]+rq[2]+rq[3]);
    }
}

// ---------------- y = relu(bn1(y)+x) -> bf16 transposed [n][tv][c] ----------
__global__ __launch_bounds__(256) void k_bn1t(
    const float* __restrict__ x, const float* __restrict__ g1, const float* __restrict__ b1,
    const float* __restrict__ s1, const float* __restrict__ s2,
    const float* __restrict__ yb, unsigned short* __restrict__ ybt)
{
    __shared__ unsigned short ls[64*66];
    int b = blockIdx.x;
    int n = b / 118, tile = b % 118;
    int tv0 = tile * 64;
    const float invN = 1.0f / (float)PCCOUNT;
    int tid = threadIdx.x;

    for (int e = tid; e < 4096; e += 256) {
        int c = e >> 6, tvl = e & 63;
        int tv = tv0 + tvl;
        unsigned short hv = 0;
        if (tv < TVsz) {
            long gi = (long)n*CTVsz + (long)c*TVsz + tv;
            float m  = s1[c] * invN;
            float vr = s2[c] * invN - m*m;
            float val = (yb[gi] - m) * rsqrtf(vr + EPSB) * g1[c] + b1[c] + x[gi];
            hv = f2bf(fmaxf(val, 0.f));
        }
        ls[tvl*66 + c] = hv;
    }
    __syncthreads();
    for (int e = tid; e < 1024; e += 256) {
        int tvl = e >> 4, c4 = (e & 15) * 4;
        int tv = tv0 + tvl;
        if (tv < TVsz) {
            unsigned int lo = *(const unsigned int*)&ls[tvl*66 + c4];
            unsigned int hi = *(const unsigned int*)&ls[tvl*66 + c4 + 2];
            *(uint2*)&ybt[((long)n*TVsz + tv)*CH + c4] = make_uint2(lo, hi);
        }
    }
}

// ---------------- temporal conv via MFMA ----------------
#define NTILE 256
#define HALO 100
#define ROWS 456

__global__ __launch_bounds__(256) void k_tconv(
    const unsigned short* __restrict__ ybt, const unsigned short* __restrict__ awT,
    const float* __restrict__ bt, unsigned short* __restrict__ ycb)
{
    __shared__ __align__(16) char ys[ROWS*128];
    int b = blockIdx.x;
    int n = b / 30, tile = b % 30;
    int tv0 = tile * NTILE;
    int tid = threadIdx.x;

    const char* src = (const char*)(ybt + (long)n * TVsz * CH);
    for (int q = tid; q < ROWS*16; q += 256) {
        int row = q >> 4;
        int cb  = (q & 15) << 3;
        int tvg = tv0 - HALO + row;
        uint2 val = make_uint2(0u, 0u);
        if (tvg >= 0 && tvg < TVsz)
            val = *(const uint2*)(src + (long)tvg*128 + cb);
        *(uint2*)(ys + row*128 + (cb ^ ((row & 7) << 4))) = val;
    }
    __syncthreads();

    int wv = tid >> 6, l = tid & 63;
    int l15 = l & 15, lhi = l >> 4;

    f32x4 acc[4][4];
    #pragma unroll
    for (int mf = 0; mf < 4; ++mf)
        #pragma unroll
        for (int nf = 0; nf < 4; ++nf)
            acc[mf][nf] = (f32x4){0.f, 0.f, 0.f, 0.f};

    const short* aw = (const short*)awT;
    for (int tap = 0; tap < KW; ++tap) {
        #pragma unroll
        for (int kc = 0; kc < 2; ++kc) {
            s16x8 af[4], bfr[4];
            #pragma unroll
            for (int mf = 0; mf < 4; ++mf)
                af[mf] = *(const s16x8*)(aw + ((tap*CH + mf*16 + l15)*CH + kc*32 + lhi*8));
            #pragma unroll
            for (int nf = 0; nf < 4; ++nf) {
                int row = wv*64 + nf*16 + l15 + tap*25;
                int cb  = (kc*64 + lhi*16) ^ ((row & 7) << 4);
                bfr[nf] = *(const s16x8*)(ys + row*128 + cb);
            }
            #pragma unroll
            for (int mf = 0; mf < 4; ++mf)
                #pragma unroll
                for (int nf = 0; nf < 4; ++nf)
                    acc[mf][nf] = __builtin_amdgcn_mfma_f32_16x16x32_bf16(
                        af[mf], bfr[nf], acc[mf][nf], 0, 0, 0);
        }
    }

    #pragma unroll
    for (int mf = 0; mf < 4; ++mf) {
        #pragma unroll
        for (int nf = 0; nf < 4; ++nf) {
            int tv = tv0 + wv*64 + nf*16 + l15;
            if (tv < TVsz) {
                #pragma unroll
                for (int r = 0; r < 4; ++r) {
                    int o = mf*16 + lhi*4 + r;
                    float v = acc[mf][nf][r] + bt[o];
                    ycb[((long)n*CH + o)*TVsz + tv] = f2bf(v);
                }
            }
        }
    }
}

// ---------------- out = relu(bn2(yc)+x), f32 ----------------
__global__ void k_out(const float* __restrict__ x, const float* __restrict__ g2, const float* __restrict__ b2,
                      const float* __restrict__ s1, const float* __restrict__ s2,
                      const unsigned short* __restrict__ ycb, float* __restrict__ out) {
    const float invN = 1.0f / (float)PCCOUNT;
    int stride = gridDim.x * blockDim.x;
    for (int i4 = blockIdx.x*blockDim.x + threadIdx.x; i4 < TOTAL/4; i4 += stride) {
        long idx = (long)i4 * 4;
        int c = (int)((idx / TVsz) & 63);
        float m  = s1[c] * invN;
        float vr = s2[c] * invN - m*m;
        float rs = rsqrtf(vr + EPSB) * g2[c];
        float bc = b2[c];
        uint2 d = *(const uint2*)(ycb + idx);
        float4 xv = *(const float4*)(x + idx);
        float4 ov;
        ov.x = fmaxf((bf2f(d.x & 0xffffu) - m)*rs + bc + xv.x, 0.f);
        ov.y = fmaxf((bf2f(d.x >> 16)     - m)*rs + bc + xv.y, 0.f);
        ov.z = fmaxf((bf2f(d.y & 0xffffu) - m)*rs + bc + xv.z, 0.f);
        ov.w = fmaxf((bf2f(d.y >> 16)     - m)*rs + bc + xv.w, 0.f);
        *(float4*)(out + idx) = ov;
    }
}

extern "C" void kernel_launch(void* const* d_in, const int* in_sizes, int n_in,
                              void* d_out, int out_size, void* d_ws, size_t ws_size,
                              hipStream_t stream) {
    const float* x  = (const float*)d_in[0];
    const float* A  = (const float*)d_in[1];
    const float* PA = (const float*)d_in[2];
    const float* Wa = (const float*)d_in[3];
    const float* ba = (const float*)d_in[4];
    const float* Wb = (const float*)d_in[5];
    const float* bb = (const float*)d_in[6];
    const float* Wd = (const float*)d_in[7];
    const float* bd = (const float*)d_in[8];
    const float* g1 = (const float*)d_in[9];
    const float* b1 = (const float*)d_in[10];
    const float* Wt = (const float*)d_in[11];
    const float* bt = (const float*)d_in[12];
    const float* g2 = (const float*)d_in[13];
    const float* b2 = (const float*)d_in[14];

    float* ws    = (float*)d_ws;
    float* Mbuf  = ws;                                        // [0, 60000)
    float* stats = ws + 60000;                                // [60000, 60256)
    unsigned short* wdcat  = (unsigned short*)(ws + 60256);   // 12288 sh -> 66400
    unsigned short* wcat   = (unsigned short*)(ws + 66400);   // 6144 sh  -> 69472
    float* biascat = ws + 69472;                              // 96       -> 69568
    unsigned short* awT    = (unsigned short*)(ws + 69568);   // 36864 sh -> 88000
    unsigned short* xbt    = (unsigned short*)(ws + 88000);   // 15.36M sh -> 7768000
    float* ybuf  = ws + 7768000;                              // 15.36M f32 -> 23128000
    unsigned short* g_c    = (unsigned short*)(ws + 23128000);// 14.74M sh -> 30500800
    // phase 2 overlays (after g/attn consumers are done):
    unsigned short* ybt = xbt;                                // 15.36M sh
    unsigned short* ycb = (unsigned short*)(ws + 23128000);   // 15.36M sh -> 30808000

    hipMemsetAsync(Mbuf, 0, (60000 + 256)*sizeof(float), stream);
    k_wpack<<<48, 256, 0, stream>>>(Wd, wdcat);
    k_wab<<<25, 256, 0, stream>>>(Wa, ba, Wb, bb, wcat, biascat);
    k_wtT<<<(CH*CH*KW + 255)/256, 256, 0, stream>>>(Wt, awT);
    k_xt<<<NB*118, 256, 0, stream>>>(x, xbt);
    k_attn<<<NSUB*NB*ATCN, 256, 0, stream>>>(xbt, wcat, biascat, Mbuf);
    k_softmax<<<NSUB*NB, 32, 0, stream>>>(A, PA, Mbuf);

    for (int ch = 0; ch < 4; ++ch) {
        int n0 = ch * NCHUNK;
        k_g<<<NCHUNK*NTILES, 256, 0, stream>>>(xbt + (long)n0*TVsz*CH, wdcat, g_c);
        k_y2<<<NCHUNK*320, 256, 0, stream>>>(g_c, Mbuf, bd, ybuf, n0);
    }

    k_bnstats<<<NB*CH, 256, 0, stream>>>(ybuf, stats, stats + 64);
    k_bn1t<<<NB*118, 256, 0, stream>>>(x, g1, b1, stats, stats + 64, ybuf, ybt);
    k_tconv<<<NB*30, 256, 0, stream>>>(ybt, awT, bt, ycb);
    k_bnstats_bf<<<NB*CH, 256, 0, stream>>>(ycb, stats + 128, stats + 192);
    k_out<<<2048, 256, 0, stream>>>(x, g2, b2, stats + 128, stats + 192, ycb, (float*)d_out);
}